// Round 5
// baseline (184.026 us; speedup 1.0000x reference)
//
#include <hip/hip_runtime.h>
#include <math.h>

// B=32768 rows, C=1000 classes, K=10 attack indices per row.
// One wave (64 lanes) per row; 4 waves per 256-thread block.
//
// Status (R3 post-mortem): kernel is memory-bound (~131 MB read in ~31 us,
// ~4.2 TB/s). VALU cuts are now worth zero (R2->R3 delta = 0). The timed
// window is ~152 us of harness ws-poison fills + the kernel. This round:
// non-temporal main-stream loads (read-once data; skip L1/L2 allocate,
// keep cache-probe semantics). R4 fix: use a native ext_vector_type for
// __builtin_nontemporal_load (HIP float4 is a class -> rejected).
//
// Structure:
//  - softmax never materialized: row max m, S=sum(exp), 10 gathered logits,
//    and max over non-attack complement suffice (exp is monotone).
//  - mNA rare-path: if max(attack logits) < max(all) (~99% of rows,
//    wave-uniform since 1 row == 1 wave) then pNA = 1/S exactly.
//  - epilogue parallelized across lanes; fp32 throughout, x^(1/p) via
//    exp2(log2(x)/p). abs err ~6e-5 vs 1.27e-3 threshold.

#define NC 1000
#define NK 10
#define NV4 250   // float4s per row; row stride 4000B is 16B-aligned
#define L2E 1.44269504088896340736f

typedef float floatx4 __attribute__((ext_vector_type(4)));

#if __has_builtin(__builtin_amdgcn_exp2f)
#define EXP2F(x) __builtin_amdgcn_exp2f(x)
#else
#define EXP2F(x) exp2f(x)
#endif
#if __has_builtin(__builtin_amdgcn_logf)
#define LOG2F(x) __builtin_amdgcn_logf(x)
#else
#define LOG2F(x) log2f(x)
#endif
#if __has_builtin(__builtin_amdgcn_rcpf)
#define RCPF(x) __builtin_amdgcn_rcpf(x)
#else
#define RCPF(x) (1.0f / (x))
#endif

__global__ __launch_bounds__(256) void boiler_loss_kernel(
    const float* __restrict__ y_pred,
    const int*   __restrict__ y_att,
    float*       __restrict__ out,
    int B)
{
    const int wave = threadIdx.x >> 6;   // 0..3
    const int lane = threadIdx.x & 63;
    const int row  = blockIdx.x * 4 + wave;
    if (row >= B) return;

    const float* __restrict__ xrow = y_pred + (size_t)row * NC;
    const int*   __restrict__ arow = y_att + (size_t)row * NK;

    // per-lane attack index (lanes >= 10 duplicate index 9: harmless for
    // max-of-attack and min-of-attack-probs)
    const int aidx = arow[lane < NK ? lane : (NK - 1)];
    const float aval = xrow[aidx];                 // cache-hit gather

    // ---- main streaming load: 250 float4s, lane + 64*k, non-temporal ----
    float v[16];
    const floatx4* __restrict__ xv = (const floatx4*)xrow;
    #pragma unroll
    for (int k = 0; k < 4; ++k) {
        const int i4 = lane + 64 * k;
        floatx4 f;
        if (i4 < NV4) f = __builtin_nontemporal_load(&xv[i4]);
        else f = (floatx4){-INFINITY, -INFINITY, -INFINITY, -INFINITY};
        v[4*k+0] = f.x; v[4*k+1] = f.y; v[4*k+2] = f.z; v[4*k+3] = f.w;
    }

    // ---- row max (fmaxf chains fuse into v_max3_f32) ----
    float mAll = fmaxf(fmaxf(fmaxf(v[0], v[1]), fmaxf(v[2], v[3])),
                       fmaxf(fmaxf(v[4], v[5]), fmaxf(v[6], v[7])));
    mAll = fmaxf(mAll,
                 fmaxf(fmaxf(fmaxf(v[8], v[9]), fmaxf(v[10], v[11])),
                       fmaxf(fmaxf(v[12], v[13]), fmaxf(v[14], v[15]))));
    float mAtt = aval;  // all 64 lanes hold an attack logit (with dups)
    #pragma unroll
    for (int off = 32; off > 0; off >>= 1) {
        mAll = fmaxf(mAll, __shfl_xor(mAll, off, 64));
        mAtt = fmaxf(mAtt, __shfl_xor(mAtt, off, 64));
    }

    // ---- sum of 2^((x-m)*log2e); padding lanes give exp2(-inf)=0 ----
    const float mscale = -mAll * L2E;
    float s = 0.0f;
    #pragma unroll
    for (int r = 0; r < 16; ++r) s += EXP2F(fmaf(v[r], L2E, mscale));
    #pragma unroll
    for (int off = 32; off > 0; off >>= 1) s += __shfl_xor(s, off, 64);

    const float rs = RCPF(s);

    // ---- pNA: max prob over the non-attack complement ----
    float pNA;
    if (mAtt < mAll) {
        // global argmax is NOT an attack element (wave-uniform, ~99% of rows)
        pNA = rs;                                   // exp(mAll-mAll)/S
    } else {
        // rare: build ownership mask and take the masked max.
        // element gi -> vec i4=gi>>2 -> lane=i4&63, reg=((i4>>6)<<2)|(gi&3)
        unsigned bits = 0u;
        #pragma unroll
        for (int j = 0; j < NK; ++j) {
            const int aj    = arow[j];              // wave-uniform -> s_load
            const int i4a   = aj >> 2;
            const int owner = i4a & 63;
            const int reg   = ((i4a >> 6) << 2) | (aj & 3);
            bits |= (owner == lane) ? (1u << reg) : 0u;
        }
        float mNA = -INFINITY;
        #pragma unroll
        for (int r = 0; r < 16; ++r)
            mNA = fmaxf(mNA, ((bits >> r) & 1u) ? -INFINITY : v[r]);
        #pragma unroll
        for (int off = 32; off > 0; off >>= 1)
            mNA = fmaxf(mNA, __shfl_xor(mNA, off, 64));
        pNA = EXP2F(fmaf(mNA, L2E, mscale)) * rs;
    }

    // ---- attack probs: lanes 0..9 hold p0..p9 (dups above) ----
    const float pj = EXP2F(fmaf(aval, L2E, mscale)) * rs;

    // pmin over attack set: dups harmless for min; lanes 0..15 hold only
    // attack probs, so a 16-group butterfly suffices.
    float pmin = pj;
    // 9th powers of (5 + 5*(p_{j+1}-p_j)) on lanes 0..8, zero elsewhere
    const float pnext = __shfl_down(pj, 1, 64);
    float t9;
    {
        const float sv = fmaf(5.0f, pnext - pj, 5.0f);   // in [0,10]
        const float x2 = sv * sv;
        const float x4 = x2 * x2;
        const float x8 = x4 * x4;
        t9 = (lane < NK - 1) ? x8 * sv : 0.0f;
    }
    #pragma unroll
    for (int off = 8; off > 0; off >>= 1) {
        pmin = fminf(pmin, __shfl_xor(pmin, off, 64));
        t9  += __shfl_xor(t9, off, 64);
    }

    if (lane == 0) {
        const float gm9 = EXP2F(LOG2F(t9 * (1.0f / 9.0f)) * (1.0f / 9.0f));
        const float sorting = (gm9 - 5.0f) * 0.2f;
        const float macro_loss = pNA - pmin;

        const float c0 = fmaf(5.0f, macro_loss, 5.0f);
        const float c1 = fmaf(5.0f, sorting, 5.0f);
        const float a2 = c0 * c0, a4 = a2 * a2, a8 = a4 * a4;
        const float b2 = c1 * c1, b4 = b2 * b2, b8 = b4 * b4;
        const float m10 = (a8 * a2 + b8 * b2) * 0.5f;
        const float gm10 = EXP2F(LOG2F(m10) * 0.1f);

        out[row] = (gm10 - 5.0f) * 0.2f;
    }
}

extern "C" void kernel_launch(void* const* d_in, const int* in_sizes, int n_in,
                              void* d_out, int out_size, void* d_ws, size_t ws_size,
                              hipStream_t stream) {
    const float* y_pred = (const float*)d_in[0];
    const int*   y_att  = (const int*)d_in[1];
    float* out = (float*)d_out;
    const int B = in_sizes[0] / NC;          // 32768
    const int blocks = (B + 3) / 4;          // 4 rows (waves) per block
    boiler_loss_kernel<<<blocks, 256, 0, stream>>>(y_pred, y_att, out, B);
}